// Round 5
// baseline (174.699 us; speedup 1.0000x reference)
//
#include <hip/hip_runtime.h>

#define L 4096
#define LMASK 4095
#define NCELL (L * L)
#define TILE 64
#define HALO 2
#define SDIM (TILE + 2 * HALO)   // 68

typedef float f32x2 __attribute__((ext_vector_type(2)));

__global__ __launch_bounds__(256) void spgg_qlearn_kernel(
    const int*    __restrict__ type_t,     // (L,L) int32, 0/1
    const float4* __restrict__ qtab,       // (N,2,2) f32 -> float4 per cell
    const float*  __restrict__ rnd,        // (N,2) f32 (tie-break only)
    const int*    __restrict__ rtype,      // (L,L) int32 0/1
    const float*  __restrict__ eps,        // (L,L) f32
    float*        __restrict__ out_type,   // (L,L) f32
    float4*       __restrict__ out_q,      // (N,2,2) f32
    float*        __restrict__ out_profit) // (L,L) f32
{
    __shared__ int s_t[SDIM * SDIM];       // 18.5 KB

    const int tx = threadIdx.x;            // 0..63 = lane (full wave per row)
    const int ty = threadIdx.y;            // 0..3  = wave id
    const int tid = ty * 64 + tx;
    const int tileR0 = blockIdx.y * TILE;
    const int tileC0 = blockIdx.x * TILE;

    // Stage 68x68 type tile with halo 2 (torus wrap, L = 2^12)
    for (int idx = tid; idx < SDIM * SDIM; idx += 256) {
        const int ly = idx / SDIM;
        const int lx = idx - ly * SDIM;
        const int gr = (tileR0 + ly - HALO) & LMASK;
        const int gc = (tileC0 + lx - HALO) & LMASK;
        s_t[idx] = type_t[gr * L + gc];
    }
    __syncthreads();

    const int gc = tileC0 + tx;
    const int sc = tx + HALO;

    #pragma unroll 4
    for (int k = 0; k < 16; ++k) {
        const int r = k * 4 + ty;          // wave ty handles rows ty, ty+4, ...
        const int gr = tileR0 + r;
        const int i = gr * L + gc;         // < 2^24, int math only

        // ---- global loads first (batched across unroll for MLP) ----
        float4 q = qtab[i];                 // [0][0],[0][1],[1][0],[1][1]
        const float e = eps[i];
        const int rt = rtype[i];

        // ---- 13-point stencil == neigh5(neigh5(c)), weights {5,2,2,1} ----
        const int sr = r + HALO;
        const int t00 = s_t[sr * SDIM + sc];
        const int cross = s_t[(sr - 1) * SDIM + sc] + s_t[(sr + 1) * SDIM + sc]
                        + s_t[sr * SDIM + sc - 1]   + s_t[sr * SDIM + sc + 1];
        const int diag  = s_t[(sr - 1) * SDIM + sc - 1] + s_t[(sr - 1) * SDIM + sc + 1]
                        + s_t[(sr + 1) * SDIM + sc - 1] + s_t[(sr + 1) * SDIM + sc + 1];
        const int far   = s_t[(sr - 2) * SDIM + sc] + s_t[(sr + 2) * SDIM + sc]
                        + s_t[sr * SDIM + sc - 2]   + s_t[sr * SDIM + sc + 2];
        const int w13 = 5 * t00 + 2 * cross + 2 * diag + far;

        // profit = (R/5)*W13 - 5*c   (R/5 = 0.96)
        const float profit = 0.96f * (float)w13 - 5.0f * (float)t00;

        const int A = t00;
        const float qa0 = A ? q.z : q.x;
        const float qa1 = A ? q.w : q.y;

        // Non-tie greedy decided by q alone (argmax over masked+rand).
        int greedy = (qa1 > qa0) ? 1 : 0;

        // Exact ties (~2 cells in 16.7M): wave-uniform scalar branch skips
        // the rnd load entirely -> the 134 MB stream costs ~0 traffic.
        if (__any(qa0 == qa1)) {
            f32x2 rv;
            asm volatile("global_load_dwordx2 %0, %1, off\n\t"
                         "s_waitcnt vmcnt(0)"
                         : "=v"(rv) : "v"(rnd + 2 * (long)i));
            if (qa0 == qa1) greedy = (rv.y > rv.x) ? 1 : 0;
        }

        const int B = (e >= 0.02f) ? greedy : rt;

        // max_a' Q[B][a'] from the ORIGINAL table
        const float qb0 = B ? q.z : q.x;
        const float qb1 = B ? q.w : q.y;
        const float maxv = fmaxf(qb0, qb1);

        // Q[A][B] <- (1-eta)*Q[A][B] + eta*(profit + gamma*maxv)
        const int ab = A * 2 + B;
        const float qab = (ab == 0) ? q.x : (ab == 1) ? q.y : (ab == 2) ? q.z : q.w;
        const float upd = 0.2f * qab + 0.8f * (profit + 0.8f * maxv);

        q.x = (ab == 0) ? upd : q.x;
        q.y = (ab == 1) ? upd : q.y;
        q.z = (ab == 2) ? upd : q.z;
        q.w = (ab == 3) ? upd : q.w;

        out_type[i]   = (float)B;
        out_q[i]      = q;
        out_profit[i] = profit;
    }
}

extern "C" void kernel_launch(void* const* d_in, const int* in_sizes, int n_in,
                              void* d_out, int out_size, void* d_ws, size_t ws_size,
                              hipStream_t stream) {
    const int*    type_t = (const int*)d_in[0];
    const float4* qtab   = (const float4*)d_in[1];
    const float*  rnd    = (const float*)d_in[2];
    const int*    rtype  = (const int*)d_in[3];
    const float*  eps    = (const float*)d_in[4];

    float* out    = (float*)d_out;
    float* o_type = out;                       // N
    float4* o_q   = (float4*)(out + NCELL);    // 4N
    float* o_prof = out + 5 * (size_t)NCELL;   // N

    dim3 block(64, 4);
    dim3 grid(L / TILE, L / TILE);             // 64 x 64 = 4096 blocks
    spgg_qlearn_kernel<<<grid, block, 0, stream>>>(
        type_t, qtab, rnd, rtype, eps, o_type, o_q, o_prof);
}

// Round 6
// 160.739 us; speedup vs baseline: 1.0869x; 1.0869x over previous
//
#include <hip/hip_runtime.h>

#define L 4096
#define LMASK 4095
#define NCELL (L * L)

typedef float f32x2 __attribute__((ext_vector_type(2)));

__global__ __launch_bounds__(256) void spgg_qlearn_kernel(
    const int*    __restrict__ type_t,     // (L,L) int32, 0/1
    const float4* __restrict__ qtab,       // (N,2,2) f32 -> float4 per cell
    const float*  __restrict__ rnd,        // (N,2) f32 (tie-break only)
    const int*    __restrict__ rtype,      // (L,L) int32 0/1
    const float*  __restrict__ eps,        // (L,L) f32
    float*        __restrict__ out_type,   // (L,L) f32
    float4*       __restrict__ out_q,      // (N,2,2) f32
    float*        __restrict__ out_profit) // (L,L) f32
{
    const int i = blockIdx.x * 256 + threadIdx.x;   // < 2^24
    const int r = i >> 12;
    const int c = i & LMASK;

    // Row bases (element index), torus wrap
    const int r0  = r << 12;
    const int rm1 = ((r - 1) & LMASK) << 12;
    const int rp1 = ((r + 1) & LMASK) << 12;
    const int rm2 = ((r - 2) & LMASK) << 12;
    const int rp2 = ((r + 2) & LMASK) << 12;
    const int cm1 = (c - 1) & LMASK;
    const int cp1 = (c + 1) & LMASK;
    const int cm2 = (c - 2) & LMASK;
    const int cp2 = (c + 2) & LMASK;

    // ---- all independent loads up front: max memory-level parallelism ----
    const int t00 = type_t[r0 + c];
    const int f1  = type_t[rm2 + c];        // far (weight 1)
    const int f2  = type_t[rp2 + c];
    const int f3  = type_t[r0 + cm2];
    const int f4  = type_t[r0 + cp2];
    const int x1  = type_t[rm1 + c];        // cross (weight 2)
    const int x2  = type_t[rp1 + c];
    const int x3  = type_t[r0 + cm1];
    const int x4  = type_t[r0 + cp1];
    const int g1  = type_t[rm1 + cm1];      // diag (weight 2)
    const int g2  = type_t[rm1 + cp1];
    const int g3  = type_t[rp1 + cm1];
    const int g4  = type_t[rp1 + cp1];

    float4 q = qtab[i];                     // [0][0],[0][1],[1][0],[1][1]
    const float e = eps[i];
    const int  rt = rtype[i];

    // 13-point stencil == neigh5(neigh5(coop)), weights {5,2(cross),2(diag),1(far)}
    const int w13 = 5 * t00 + 2 * (x1 + x2 + x3 + x4) + 2 * (g1 + g2 + g3 + g4)
                  + (f1 + f2 + f3 + f4);

    // profit = (R/5)*W13 - 5*c    (R/5 = 0.96)
    const float profit = 0.96f * (float)w13 - 5.0f * (float)t00;

    const int A = t00;
    const float qa0 = A ? q.z : q.x;
    const float qa1 = A ? q.w : q.y;

    // Non-tie greedy decided by q alone (argmax over masked+rand).
    int greedy = (qa1 > qa0) ? 1 : 0;

    // Exact ties (~1 cell in 16.7M): wave-uniform scalar branch skips the
    // rnd load entirely -> 134 MB stream costs ~0 traffic, ~0 stalls.
    if (__any(qa0 == qa1)) {
        f32x2 rv;
        asm volatile("global_load_dwordx2 %0, %1, off\n\t"
                     "s_waitcnt vmcnt(0)"
                     : "=v"(rv) : "v"(rnd + 2 * (long)i));
        if (qa0 == qa1) greedy = (rv.y > rv.x) ? 1 : 0;
    }

    const int B = (e >= 0.02f) ? greedy : rt;

    // max_a' Q[B][a'] from the ORIGINAL table
    const float qb0 = B ? q.z : q.x;
    const float qb1 = B ? q.w : q.y;
    const float maxv = fmaxf(qb0, qb1);

    // Q[A][B] <- (1-eta)*Q[A][B] + eta*(profit + gamma*maxv)
    const int ab = A * 2 + B;
    const float qab = (ab == 0) ? q.x : (ab == 1) ? q.y : (ab == 2) ? q.z : q.w;
    const float upd = 0.2f * qab + 0.8f * (profit + 0.8f * maxv);

    q.x = (ab == 0) ? upd : q.x;
    q.y = (ab == 1) ? upd : q.y;
    q.z = (ab == 2) ? upd : q.z;
    q.w = (ab == 3) ? upd : q.w;

    out_type[i]   = (float)B;
    out_q[i]      = q;
    out_profit[i] = profit;
}

extern "C" void kernel_launch(void* const* d_in, const int* in_sizes, int n_in,
                              void* d_out, int out_size, void* d_ws, size_t ws_size,
                              hipStream_t stream) {
    const int*    type_t = (const int*)d_in[0];
    const float4* qtab   = (const float4*)d_in[1];
    const float*  rnd    = (const float*)d_in[2];
    const int*    rtype  = (const int*)d_in[3];
    const float*  eps    = (const float*)d_in[4];

    float* out    = (float*)d_out;
    float* o_type = out;                       // N
    float4* o_q   = (float4*)(out + NCELL);    // 4N
    float* o_prof = out + 5 * (size_t)NCELL;   // N

    // 1D: 65536 blocks x 256 threads. 16 blocks/row, 16 % 8 == 0 ->
    // vertical-neighbor blocks (b +/- 16) map to the SAME XCD: no
    // cross-XCD refetch of type rows. Do NOT swizzle blockIdx.
    spgg_qlearn_kernel<<<NCELL / 256, 256, 0, stream>>>(
        type_t, qtab, rnd, rtype, eps, o_type, o_q, o_prof);
}